// Round 3
// baseline (695.751 us; speedup 1.0000x reference)
//
#include <hip/hip_runtime.h>
#include <cmath>

// DeepSeek MoE layer, MI355X (gfx950). Round 6.
// B=2,S=1024 -> T=2048 tokens. H=1024, FF=4096, E=64, K=8, M=512.
//
// Round-6 changes vs round 5 (MfmaUtil pinned ~8.7% across 3 different
// schedules; SQ_LDS_BANK_CONFLICT 3.5M/dispatch; VALUBusy 24% vs MFMA 9%):
//  - LDS chunk-XOR swizzle (T2 adapted to global_load_lds, rule #21):
//    logical chunk c of row r stored at physical chunk c^((r>>1)&3).
//    Linear LDS dest (required by global_load_lds), inverse permute on
//    the per-lane GLOBAL source (sc), forward permute on the ds_read
//    offset (qs). Fragment reads become bank-conflict-free (each 8-lane
//    phase covers all 8 16B slots exactly once).
//  - Static 3-buffer indices: K-loop fully unrolled (KITERS literal),
//    buffer = t%3 constant-folded. Kills the runtime ri/ni/si address
//    recomputation (VALU churn) -> ds_read base+immediate.
//  - Pipeline structure unchanged from r5 (counted vmcnt(3), 1 barrier
//    per iter, 3-buffer depth-2, verified race-safe).

typedef _Float16 f16;
typedef __attribute__((ext_vector_type(4))) _Float16 f16x4;
typedef __attribute__((ext_vector_type(8))) _Float16 f16x8;
typedef __attribute__((ext_vector_type(4))) float f32x4;

#define NT 2048      // tokens
#define HD 1024      // hidden
#define FF 4096      // shared intermediate
#define NE 64        // experts
#define TOPK 8
#define MD 512       // moe intermediate

// ---- workspace layout (bytes) ----
constexpr size_t SZ_H1 = (size_t)NT * FF * 2;                // fp16 [2048][4096]
constexpr size_t SZ_HX = (size_t)(NT * TOPK + 128) * MD * 2; // fp16 [16512][512]
constexpr size_t O_H1 = 0;
constexpr size_t O_HX = O_H1 + SZ_H1;
constexpr size_t O_TOPKI = O_HX + SZ_HX;
constexpr size_t O_TOPKW = O_TOPKI + (size_t)NT * TOPK * 4;
constexpr size_t O_COUNTS = O_TOPKW + (size_t)NT * TOPK * 4;
constexpr size_t O_CURSORS = O_COUNTS + 256;
constexpr size_t O_OFFSETS = O_CURSORS + 256;
constexpr size_t O_RTOK = O_OFFSETS + 256;
constexpr size_t O_RW = O_RTOK + (size_t)NT * TOPK * 4;
constexpr size_t O_XH = ((O_RW + (size_t)NT * TOPK * 4 + 255) / 256) * 256;
constexpr size_t O_W1T = O_XH + (size_t)NT * HD * 2;         // fp16 [E][M][H]
constexpr size_t O_W2T = O_W1T + (size_t)NE * HD * MD * 2;   // fp16 [E][H][M]
constexpr size_t O_WS1T = O_W2T + (size_t)NE * MD * HD * 2;  // fp16 [FF][H]
constexpr size_t O_WS2T = O_WS1T + (size_t)HD * FF * 2;      // fp16 [H][FF]
constexpr size_t WS_NEEDED = O_WS2T + (size_t)FF * HD * 2;   // ~189 MB

// async global->LDS, 16B per lane; lane i lands at ldsbase + i*16.
__device__ __forceinline__ void lds16(void* l, const void* g) {
    __builtin_amdgcn_global_load_lds(
        (const __attribute__((address_space(1))) void*)g,
        (__attribute__((address_space(3))) void*)l, 16, 0, 0);
}

// ------------------------------------------------------------------
// router: logits[t][e] = dot(x[t], Wg[:,e]) in fp32 (must match numpy top-k).
__global__ __launch_bounds__(256) void k_router(const float* __restrict__ X,
                                                const float* __restrict__ Wg,
                                                float* __restrict__ logits)
{
    __shared__ float xs[4][HD];
    const int tid = threadIdx.x;
    const int t0 = blockIdx.x * 4;
    #pragma unroll
    for (int i = 0; i < 4; ++i) {
        int f4 = tid + i * 256;
        int row = f4 >> 8;
        int col = (f4 & 255) * 4;
        *(float4*)&xs[row][col] = *(const float4*)&X[(t0 + row) * HD + col];
    }
    __syncthreads();
    const int e = tid & 63, tok = tid >> 6;
    float a0 = 0.f, a1 = 0.f, a2 = 0.f, a3 = 0.f;
    const float* xr = xs[tok];
    for (int h = 0; h < HD; h += 4) {
        a0 += xr[h + 0] * Wg[(h + 0) * NE + e];
        a1 += xr[h + 1] * Wg[(h + 1) * NE + e];
        a2 += xr[h + 2] * Wg[(h + 2) * NE + e];
        a3 += xr[h + 3] * Wg[(h + 3) * NE + e];
    }
    logits[(t0 + tok) * NE + e] = (a0 + a1) + (a2 + a3);
}

// top-8 + softmax per token; one wave per token; tie-break lower index.
__global__ __launch_bounds__(64) void k_topk(const float* __restrict__ logits,
                                             int* __restrict__ topk_idx,
                                             float* __restrict__ topk_w,
                                             int* __restrict__ counts)
{
    const int t = blockIdx.x;
    const int lane = threadIdx.x;
    __shared__ float sval[TOPK];
    __shared__ int sidx[TOPK];
    float cur = logits[t * NE + lane];
    for (int it = 0; it < TOPK; ++it) {
        float v = cur; int id = lane;
        #pragma unroll
        for (int off = 32; off > 0; off >>= 1) {
            float ov = __shfl_xor(v, off, 64);
            int   oi = __shfl_xor(id, off, 64);
            if (ov > v || (ov == v && oi < id)) { v = ov; id = oi; }
        }
        if (lane == 0) { sval[it] = v; sidx[it] = id; }
        if (lane == id) cur = -INFINITY;
    }
    __syncthreads();
    if (lane < TOPK) {
        float m = sval[0];
        float denom = 0.f;
        #pragma unroll
        for (int j = 0; j < TOPK; ++j) denom += expf(sval[j] - m);
        float w = expf(sval[lane] - m) / denom;
        int e = sidx[lane];
        topk_idx[t * TOPK + lane] = e;
        topk_w[t * TOPK + lane] = w;
        atomicAdd(&counts[e], 1);
    }
}

__global__ void k_scan(const int* __restrict__ counts, int* __restrict__ offsets)
{
    if (threadIdx.x == 0) {
        int run = 0;
        for (int e = 0; e < NE; ++e) { offsets[e] = run; run += counts[e]; }
    }
}

__global__ __launch_bounds__(256) void k_route(const int* __restrict__ topk_idx,
                                               const float* __restrict__ topk_w,
                                               const int* __restrict__ offsets,
                                               int* __restrict__ cursors,
                                               int* __restrict__ rtok,
                                               float* __restrict__ rw)
{
    int i = blockIdx.x * 256 + threadIdx.x;
    int e = topk_idx[i];
    int pos = atomicAdd(&cursors[e], 1);
    int slot = offsets[e] + pos;
    rtok[slot] = i >> 3;
    rw[slot] = topk_w[i];
}

// ------------------------------------------------------------------
// conversion pre-pass
__global__ __launch_bounds__(256) void k_cvt_x(const float* __restrict__ X,
                                               f16* __restrict__ Xh)
{
    int i = blockIdx.x * 256 + threadIdx.x;
    float4 v = ((const float4*)X)[i];
    f16x4 h = { (f16)v.x, (f16)v.y, (f16)v.z, (f16)v.w };
    ((f16x4*)Xh)[i] = h;
}

// fp32 [K][N] -> fp16 [N][K] (transpose), batched over blockIdx.z.
__global__ __launch_bounds__(256) void k_cvt_t(const float* __restrict__ src,
                                               f16* __restrict__ dst,
                                               int K, int N)
{
    const size_t bofs = (size_t)blockIdx.z * K * N;
    src += bofs; dst += bofs;
    const int n0 = blockIdx.x * 64, k0 = blockIdx.y * 64;
    __shared__ f16 t[64][68];
    const int tid = threadIdx.x;
    #pragma unroll
    for (int i = 0; i < 4; ++i) {
        int idx = tid + i * 256;
        int r = idx >> 4, c4 = (idx & 15) * 4;
        float4 v = *(const float4*)&src[(size_t)(k0 + r) * N + n0 + c4];
        f16x4 h = { (f16)v.x, (f16)v.y, (f16)v.z, (f16)v.w };
        *(f16x4*)&t[r][c4] = h;
    }
    __syncthreads();
    #pragma unroll
    for (int i = 0; i < 4; ++i) {
        int idx = tid + i * 256;
        int nr = idx >> 4, kc = (idx & 15) * 4;
        f16x4 o = { t[kc][nr], t[kc + 1][nr], t[kc + 2][nr], t[kc + 3][nr] };
        *(f16x4*)&dst[(size_t)(n0 + nr) * K + k0 + kc] = o;
    }
}

// ------------------------------------------------------------------
// GEMM core: 64x128 tile, BK=32, 4 waves (2 M-halves x 2 N-halves),
// wave = 32x64 = acc[2][4]. 3-buffer depth-2 pipeline, counted vmcnt,
// raw s_barrier (one per iter). LDS/buffer: As 64x32, Bs 128x32 (12KB).
// Frag mapping (verified r0-r5): A[m=fr][k=q*8+j], B[n=fr][k=q*8+j],
// C/D col=fr, row=q*4+reg.
//
// LDS swizzle: logical (row, chunk c of 4x16B) stored at physical chunk
// c ^ ((row>>1)&3).  Staging keeps the LINEAR global_load_lds dest
// (lane l -> row l>>2, phys chunk l&3) and permutes the global SOURCE:
// lane l loads logical chunk (l&3)^((l>>3)&3) of its row (sc below).
// Reads apply the forward permute: f16 offset (q ^ ((fr>>1)&3))*8 (qs).
// All fragment row bases are multiples of 16, so the permute term
// depends only on fr/lane -> wave-invariant. Bank check: slot(bank/4)
// = (fr&1)*4 + q^((fr>>1)&3); every contiguous 8-lane phase covers all
// 8 slots exactly once -> conflict-free.

#define GEMM_PREAMBLE                                                        \
    const int tid = threadIdx.x, lane = tid & 63, wave = tid >> 6;           \
    const int wm = (wave >> 1) * 32, wn = (wave & 1) * 64;                   \
    const int fr = lane & 15, q = lane >> 4;                                 \
    const int qs = (q ^ ((fr >> 1) & 3)) * 8;                                \
    const int sr = lane >> 2;                                                \
    const int sc = ((lane & 3) ^ ((lane >> 3) & 3)) * 8;

#define GEMM_LDS                                                             \
    __shared__ alignas(16) f16 As[3][64 * 32];                               \
    __shared__ alignas(16) f16 Bs[3][128 * 32];

// one stage = 3 global_load_lds instructions per thread (12KB/tile).
#define GEMM_STAGE(si, ofs)                                                  \
    lds16(&As[si][wave * 16 * 32], gA + (ofs));                              \
    lds16(&Bs[si][wave * 32 * 32], gB0 + (ofs));                             \
    lds16(&Bs[si][(wave * 32 + 16) * 32], gB1 + (ofs));

#define GEMM_MFMA(ri)                                                        \
    {                                                                        \
        f16x8 af[2], bf[4];                                                  \
        _Pragma("unroll")                                                    \
        for (int i = 0; i < 2; ++i)                                          \
            af[i] = *(const f16x8*)&As[ri][(wm + i * 16 + fr) * 32 + qs];    \
        _Pragma("unroll")                                                    \
        for (int j = 0; j < 4; ++j)                                          \
            bf[j] = *(const f16x8*)&Bs[ri][(wn + j * 16 + fr) * 32 + qs];    \
        _Pragma("unroll")                                                    \
        for (int i = 0; i < 2; ++i)                                          \
            _Pragma("unroll")                                                \
            for (int j = 0; j < 4; ++j)                                      \
                acc[i][j] = __builtin_amdgcn_mfma_f32_16x16x32_f16(          \
                    af[i], bf[j], acc[i][j], 0, 0, 0);                       \
    }

// Pipelined K-loop, FULLY UNROLLED (KITERS is a literal at every call
// site) so buffer indices t%3 and stage offsets constant-fold.
// Steady state: wait vmcnt(3) [stage t landed; stage t+1 (3 loads) in
// flight], barrier, issue stage t+2, compute tile t. vmcnt drains to 0
// only on the final iteration. Race safety unchanged from r4/r5
// (verified): each wave waits its own stage-t vmcnt before the barrier;
// a buffer re-staged at iter t was last read at iter t-1 and all waves'
// ds_reads from it completed before their MFMAs, hence before barrier t.
#define GEMM_LOOP(KITERS)                                                    \
    GEMM_STAGE(0, 0)                                                         \
    GEMM_STAGE(1, 32)                                                        \
    _Pragma("unroll")                                                        \
    for (int t = 0; t < (KITERS); ++t) {                                     \
        if (t < (KITERS) - 1)                                                \
            asm volatile("s_waitcnt vmcnt(3)" ::: "memory");                 \
        else                                                                 \
            asm volatile("s_waitcnt vmcnt(0)" ::: "memory");                 \
        __builtin_amdgcn_s_barrier();                                        \
        asm volatile("" ::: "memory");                                       \
        if (t + 2 < (KITERS)) { GEMM_STAGE((t + 2) % 3, (t + 2) * 32) }      \
        GEMM_MFMA(t % 3)                                                     \
    }

// shared GEMM1: H1 = silu(Xh @ Ws1), fp16. M=2048 N=4096 K=1024.
__global__ __launch_bounds__(256) void g_shared1(const f16* __restrict__ Xh,
                                                 const f16* __restrict__ Bt,  // [FF][HD]
                                                 f16* __restrict__ H1)
{
    GEMM_LDS
    GEMM_PREAMBLE
    const int m0 = blockIdx.y * 64, n0 = blockIdx.x * 128;
    const f16* gA = Xh + (size_t)(m0 + wave * 16 + sr) * HD + sc;
    const f16* gB0 = Bt + (size_t)(n0 + wave * 32 + sr) * HD + sc;
    const f16* gB1 = gB0 + (size_t)16 * HD;

    f32x4 acc[2][4] = {};
    GEMM_LOOP(32)

    #pragma unroll
    for (int i = 0; i < 2; ++i)
        #pragma unroll
        for (int j = 0; j < 4; ++j)
            #pragma unroll
            for (int r = 0; r < 4; ++r) {
                int m = m0 + wm + i * 16 + q * 4 + r;
                int n = n0 + wn + j * 16 + fr;
                float v = acc[i][j][r];
                H1[(size_t)m * FF + n] = (f16)(v / (1.f + expf(-v)));
            }
}

// shared GEMM2: Out += H1 @ Ws2, split-K=4 atomics. M=2048 N=1024 K=4096.
__global__ __launch_bounds__(256) void g_shared2(const f16* __restrict__ H1,
                                                 const f16* __restrict__ Bt,  // [HD][FF]
                                                 float* __restrict__ Out)
{
    GEMM_LDS
    GEMM_PREAMBLE
    const int m0 = blockIdx.y * 64, n0 = blockIdx.x * 128;
    const int kbase = blockIdx.z * (FF / 4);
    const f16* gA = H1 + (size_t)(m0 + wave * 16 + sr) * FF + kbase + sc;
    const f16* gB0 = Bt + (size_t)(n0 + wave * 32 + sr) * FF + kbase + sc;
    const f16* gB1 = gB0 + (size_t)16 * FF;

    f32x4 acc[2][4] = {};
    GEMM_LOOP(32)

    #pragma unroll
    for (int i = 0; i < 2; ++i)
        #pragma unroll
        for (int j = 0; j < 4; ++j)
            #pragma unroll
            for (int r = 0; r < 4; ++r) {
                int m = m0 + wm + i * 16 + q * 4 + r;
                int n = n0 + wn + j * 16 + fr;
                atomicAdd(&Out[(size_t)m * HD + n], acc[i][j][r]);
            }
}

// expert GEMM1: Hx[slot] = silu(Xh[rtok[slot]] @ W1[e]) fp16. K=1024 N=512.
__global__ __launch_bounds__(256) void g_exp1(const f16* __restrict__ Xh,
                                              const f16* __restrict__ W1t, // [E][M][H]
                                              const int* __restrict__ counts,
                                              const int* __restrict__ offsets,
                                              const int* __restrict__ rtok,
                                              f16* __restrict__ Hx)
{
    const int e = blockIdx.z;
    const int cnt = counts[e];
    const int mt = blockIdx.y * 64;
    if (mt >= cnt) return;
    const int off = offsets[e];
    const int n0 = blockIdx.x * 128;
    const f16* W = W1t + (size_t)e * MD * HD;

    GEMM_LDS
    GEMM_PREAMBLE

    int rm = mt + wave * 16 + sr;
    int s0 = off + (rm < cnt ? rm : cnt - 1);
    const f16* gA = Xh + (size_t)rtok[s0] * HD + sc;
    const f16* gB0 = W + (size_t)(n0 + wave * 32 + sr) * HD + sc;
    const f16* gB1 = gB0 + (size_t)16 * HD;

    f32x4 acc[2][4] = {};
    GEMM_LOOP(32)

    #pragma unroll
    for (int i = 0; i < 2; ++i)
        #pragma unroll
        for (int j = 0; j < 4; ++j)
            #pragma unroll
            for (int r = 0; r < 4; ++r) {
                int m_in = mt + wm + i * 16 + q * 4 + r;
                if (m_in < cnt) {
                    int n = n0 + wn + j * 16 + fr;
                    float v = acc[i][j][r];
                    Hx[(size_t)(off + m_in) * MD + n] = (f16)(v / (1.f + expf(-v)));
                }
            }
}

// expert GEMM2: Out[t] += w * (Hx @ W2[e]). K=512 N=1024, atomic scatter.
__global__ __launch_bounds__(256) void g_exp2(const f16* __restrict__ Hx,
                                              const f16* __restrict__ W2t, // [E][H][M]
                                              const int* __restrict__ counts,
                                              const int* __restrict__ offsets,
                                              const int* __restrict__ rtok,
                                              const float* __restrict__ rw,
                                              float* __restrict__ Out)
{
    const int e = blockIdx.z;
    const int cnt = counts[e];
    const int mt = blockIdx.y * 64;
    if (mt >= cnt) return;
    const int off = offsets[e];
    const int n0 = blockIdx.x * 128;
    const f16* W = W2t + (size_t)e * HD * MD;

    GEMM_LDS
    GEMM_PREAMBLE

    // A rows are packed slots; Hx pad rows (128) make OOB reads safe
    // (masked at C).
    const f16* gA = Hx + (size_t)(off + mt + wave * 16 + sr) * MD + sc;
    const f16* gB0 = W + (size_t)(n0 + wave * 32 + sr) * MD + sc;
    const f16* gB1 = gB0 + (size_t)16 * MD;

    f32x4 acc[2][4] = {};
    GEMM_LOOP(16)

    #pragma unroll
    for (int i = 0; i < 2; ++i)
        #pragma unroll
        for (int r = 0; r < 4; ++r) {
            int m_in = mt + wm + i * 16 + q * 4 + r;
            if (m_in < cnt) {
                int slot = off + m_in;
                int t = rtok[slot];
                float w = rw[slot];
                float* orow = Out + (size_t)t * HD + n0 + wn + fr;
                #pragma unroll
                for (int j = 0; j < 4; ++j)
                    atomicAdd(&orow[j * 16], w * acc[i][j][r]);
            }
        }
}

// ------------------------------------------------------------------
extern "C" void kernel_launch(void* const* d_in, const int* in_sizes, int n_in,
                              void* d_out, int out_size, void* d_ws, size_t ws_size,
                              hipStream_t stream)
{
    (void)in_sizes; (void)n_in; (void)out_size; (void)ws_size;
    const float* X   = (const float*)d_in[0];
    const float* Ws1 = (const float*)d_in[1];
    const float* Ws2 = (const float*)d_in[2];
    const float* Wg  = (const float*)d_in[3];
    const float* W1  = (const float*)d_in[4];
    const float* W2  = (const float*)d_in[5];
    float* out = (float*)d_out;
    float* logits = out + (size_t)NT * HD;

    char* ws = (char*)d_ws;
    f16*   h1       = (f16*)(ws + O_H1);
    f16*   hx       = (f16*)(ws + O_HX);
    int*   topk_idx = (int*)(ws + O_TOPKI);
    float* topk_w   = (float*)(ws + O_TOPKW);
    int*   counts   = (int*)(ws + O_COUNTS);
    int*   cursors  = (int*)(ws + O_CURSORS);
    int*   offsets  = (int*)(ws + O_OFFSETS);
    int*   rtok     = (int*)(ws + O_RTOK);
    float* rwt      = (float*)(ws + O_RW);
    f16*   xh       = (f16*)(ws + O_XH);
    f16*   w1t      = (f16*)(ws + O_W1T);
    f16*   w2t      = (f16*)(ws + O_W2T);
    f16*   ws1t     = (f16*)(ws + O_WS1T);
    f16*   ws2t     = (f16*)(ws + O_WS2T);

    hipMemsetAsync(counts, 0, 512, stream);   // counts + cursors

    k_router<<<NT / 4, 256, 0, stream>>>(X, Wg, logits);
    k_topk<<<NT, 64, 0, stream>>>(logits, topk_idx, topk_w, counts);
    k_scan<<<1, 64, 0, stream>>>(counts, offsets);
    k_route<<<NT * TOPK / 256, 256, 0, stream>>>(topk_idx, topk_w, offsets, cursors, rtok, rwt);

    // conversion pre-pass
    k_cvt_x<<<NT * HD / 1024, 256, 0, stream>>>(X, xh);
    k_cvt_t<<<dim3(FF / 64, HD / 64, 1), 256, 0, stream>>>(Ws1, ws1t, HD, FF);
    k_cvt_t<<<dim3(HD / 64, FF / 64, 1), 256, 0, stream>>>(Ws2, ws2t, FF, HD);
    k_cvt_t<<<dim3(MD / 64, HD / 64, NE), 256, 0, stream>>>(W1, w1t, HD, MD);
    k_cvt_t<<<dim3(HD / 64, MD / 64, NE), 256, 0, stream>>>(W2, w2t, MD, HD);
    hipMemsetAsync(out, 0, (size_t)NT * HD * 4, stream);

    g_shared1<<<dim3(FF / 128, NT / 64), 256, 0, stream>>>(xh, ws1t, h1);
    g_shared2<<<dim3(HD / 128, NT / 64, 4), 256, 0, stream>>>(h1, ws2t, out);
    g_exp1<<<dim3(MD / 128, NT / 64, NE), 256, 0, stream>>>(xh, w1t, counts, offsets, rtok, hx);
    g_exp2<<<dim3(HD / 128, NT / 64, NE), 256, 0, stream>>>(hx, w2t, counts, offsets, rtok, rwt, out);
}

// Round 4
// 650.265 us; speedup vs baseline: 1.0700x; 1.0700x over previous
//
#include <hip/hip_runtime.h>
#include <cmath>

// DeepSeek MoE layer, MI355X (gfx950). Round 7.
// B=2,S=1024 -> T=2048 tokens. H=1024, FF=4096, E=64, K=8, M=512.
//
// Round-7 changes vs round 6 (bank conflicts -> 0 and VALU 24->11% but
// time unchanged; MfmaUtil pinned ~8.5% across 5 schedules => the
// binding constraint is load-latency exposure per tiny BK=32 work
// quantum, not scheduling/conflicts/VALU):
//  - GEMM core -> m97 geometry: 128x128 tile, BK=32, 4 waves (2x2 of
//    64x64), acc[4][4]: 16 MFMA : 8 ds_read per wave-iter, 2x the
//    arithmetic per staged byte of r5/r6's 64x128 tile.
//  - Expert kernels: 1-D grid with XCD-residue swizzle -- every block
//    of expert e has linear ID == e%8 (mod 8), so the whole expert's
//    W slice becomes L2-resident on one XCD (load latency ~900 -> ~200
//    cy after first touch). Full y-coverage (cnt <= 2048), early-return
//    blocks are ~free. Heuristic-only mapping: wrong mapping costs
//    locality, never correctness.
//  - Pipeline + LDS swizzle unchanged from r6 (counted vmcnt, now
//    vmcnt(4) for the 4-load stage; 3 buffers; chunk-XOR swizzle with
//    linear global_load_lds dest / permuted global source / permuted
//    ds_read offset). LDS 3 x 16KB = 48KB -> 3 blocks/CU cap.

typedef _Float16 f16;
typedef __attribute__((ext_vector_type(4))) _Float16 f16x4;
typedef __attribute__((ext_vector_type(8))) _Float16 f16x8;
typedef __attribute__((ext_vector_type(4))) float f32x4;

#define NT 2048      // tokens
#define HD 1024      // hidden
#define FF 4096      // shared intermediate
#define NE 64        // experts
#define TOPK 8
#define MD 512       // moe intermediate

// ---- workspace layout (bytes) ----
constexpr size_t SZ_H1 = (size_t)NT * FF * 2;                // fp16 [2048][4096]
constexpr size_t SZ_HX = (size_t)(NT * TOPK + 128) * MD * 2; // fp16 [16512][512]
constexpr size_t O_H1 = 0;
constexpr size_t O_HX = O_H1 + SZ_H1;
constexpr size_t O_TOPKI = O_HX + SZ_HX;
constexpr size_t O_TOPKW = O_TOPKI + (size_t)NT * TOPK * 4;
constexpr size_t O_COUNTS = O_TOPKW + (size_t)NT * TOPK * 4;
constexpr size_t O_CURSORS = O_COUNTS + 256;
constexpr size_t O_OFFSETS = O_CURSORS + 256;
constexpr size_t O_RTOK = O_OFFSETS + 256;
constexpr size_t O_RW = O_RTOK + (size_t)NT * TOPK * 4;
constexpr size_t O_XH = ((O_RW + (size_t)NT * TOPK * 4 + 255) / 256) * 256;
constexpr size_t O_W1T = O_XH + (size_t)NT * HD * 2;         // fp16 [E][M][H]
constexpr size_t O_W2T = O_W1T + (size_t)NE * HD * MD * 2;   // fp16 [E][H][M]
constexpr size_t O_WS1T = O_W2T + (size_t)NE * MD * HD * 2;  // fp16 [FF][H]
constexpr size_t O_WS2T = O_WS1T + (size_t)HD * FF * 2;      // fp16 [H][FF]
constexpr size_t WS_NEEDED = O_WS2T + (size_t)FF * HD * 2;   // ~189 MB

// async global->LDS, 16B per lane; lane i lands at ldsbase + i*16.
__device__ __forceinline__ void lds16(void* l, const void* g) {
    __builtin_amdgcn_global_load_lds(
        (const __attribute__((address_space(1))) void*)g,
        (__attribute__((address_space(3))) void*)l, 16, 0, 0);
}

// ------------------------------------------------------------------
// router: logits[t][e] = dot(x[t], Wg[:,e]) in fp32 (must match numpy top-k).
__global__ __launch_bounds__(256) void k_router(const float* __restrict__ X,
                                                const float* __restrict__ Wg,
                                                float* __restrict__ logits)
{
    __shared__ float xs[4][HD];
    const int tid = threadIdx.x;
    const int t0 = blockIdx.x * 4;
    #pragma unroll
    for (int i = 0; i < 4; ++i) {
        int f4 = tid + i * 256;
        int row = f4 >> 8;
        int col = (f4 & 255) * 4;
        *(float4*)&xs[row][col] = *(const float4*)&X[(t0 + row) * HD + col];
    }
    __syncthreads();
    const int e = tid & 63, tok = tid >> 6;
    float a0 = 0.f, a1 = 0.f, a2 = 0.f, a3 = 0.f;
    const float* xr = xs[tok];
    for (int h = 0; h < HD; h += 4) {
        a0 += xr[h + 0] * Wg[(h + 0) * NE + e];
        a1 += xr[h + 1] * Wg[(h + 1) * NE + e];
        a2 += xr[h + 2] * Wg[(h + 2) * NE + e];
        a3 += xr[h + 3] * Wg[(h + 3) * NE + e];
    }
    logits[(t0 + tok) * NE + e] = (a0 + a1) + (a2 + a3);
}

// top-8 + softmax per token; one wave per token; tie-break lower index.
__global__ __launch_bounds__(64) void k_topk(const float* __restrict__ logits,
                                             int* __restrict__ topk_idx,
                                             float* __restrict__ topk_w,
                                             int* __restrict__ counts)
{
    const int t = blockIdx.x;
    const int lane = threadIdx.x;
    __shared__ float sval[TOPK];
    __shared__ int sidx[TOPK];
    float cur = logits[t * NE + lane];
    for (int it = 0; it < TOPK; ++it) {
        float v = cur; int id = lane;
        #pragma unroll
        for (int off = 32; off > 0; off >>= 1) {
            float ov = __shfl_xor(v, off, 64);
            int   oi = __shfl_xor(id, off, 64);
            if (ov > v || (ov == v && oi < id)) { v = ov; id = oi; }
        }
        if (lane == 0) { sval[it] = v; sidx[it] = id; }
        if (lane == id) cur = -INFINITY;
    }
    __syncthreads();
    if (lane < TOPK) {
        float m = sval[0];
        float denom = 0.f;
        #pragma unroll
        for (int j = 0; j < TOPK; ++j) denom += expf(sval[j] - m);
        float w = expf(sval[lane] - m) / denom;
        int e = sidx[lane];
        topk_idx[t * TOPK + lane] = e;
        topk_w[t * TOPK + lane] = w;
        atomicAdd(&counts[e], 1);
    }
}

__global__ void k_scan(const int* __restrict__ counts, int* __restrict__ offsets)
{
    if (threadIdx.x == 0) {
        int run = 0;
        for (int e = 0; e < NE; ++e) { offsets[e] = run; run += counts[e]; }
    }
}

__global__ __launch_bounds__(256) void k_route(const int* __restrict__ topk_idx,
                                               const float* __restrict__ topk_w,
                                               const int* __restrict__ offsets,
                                               int* __restrict__ cursors,
                                               int* __restrict__ rtok,
                                               float* __restrict__ rw)
{
    int i = blockIdx.x * 256 + threadIdx.x;
    int e = topk_idx[i];
    int pos = atomicAdd(&cursors[e], 1);
    int slot = offsets[e] + pos;
    rtok[slot] = i >> 3;
    rw[slot] = topk_w[i];
}

// ------------------------------------------------------------------
// conversion pre-pass
__global__ __launch_bounds__(256) void k_cvt_x(const float* __restrict__ X,
                                               f16* __restrict__ Xh)
{
    int i = blockIdx.x * 256 + threadIdx.x;
    float4 v = ((const float4*)X)[i];
    f16x4 h = { (f16)v.x, (f16)v.y, (f16)v.z, (f16)v.w };
    ((f16x4*)Xh)[i] = h;
}

// fp32 [K][N] -> fp16 [N][K] (transpose), batched over blockIdx.z.
__global__ __launch_bounds__(256) void k_cvt_t(const float* __restrict__ src,
                                               f16* __restrict__ dst,
                                               int K, int N)
{
    const size_t bofs = (size_t)blockIdx.z * K * N;
    src += bofs; dst += bofs;
    const int n0 = blockIdx.x * 64, k0 = blockIdx.y * 64;
    __shared__ f16 t[64][68];
    const int tid = threadIdx.x;
    #pragma unroll
    for (int i = 0; i < 4; ++i) {
        int idx = tid + i * 256;
        int r = idx >> 4, c4 = (idx & 15) * 4;
        float4 v = *(const float4*)&src[(size_t)(k0 + r) * N + n0 + c4];
        f16x4 h = { (f16)v.x, (f16)v.y, (f16)v.z, (f16)v.w };
        *(f16x4*)&t[r][c4] = h;
    }
    __syncthreads();
    #pragma unroll
    for (int i = 0; i < 4; ++i) {
        int idx = tid + i * 256;
        int nr = idx >> 4, kc = (idx & 15) * 4;
        f16x4 o = { t[kc][nr], t[kc + 1][nr], t[kc + 2][nr], t[kc + 3][nr] };
        *(f16x4*)&dst[(size_t)(n0 + nr) * K + k0 + kc] = o;
    }
}

// ------------------------------------------------------------------
// GEMM core: 128x128 tile, BK=32, 4 waves (2 M-halves x 2 N-halves),
// wave = 64x64 = acc[4][4]. 3-buffer depth-2 pipeline, counted vmcnt,
// raw s_barrier (one per iter). LDS/buffer: As 128x32, Bs 128x32 (16KB).
// Frag mapping (verified r0-r6): A[m=fr][k=q*8+j], B[n=fr][k=q*8+j],
// C/D col=fr, row=q*4+reg.
//
// LDS swizzle (verified r6: SQ_LDS_BANK_CONFLICT -> 0): logical chunk c
// (of 4x16B per row) stored at physical chunk c^((row>>1)&3). Linear
// global_load_lds dest (lane l -> row l>>2, phys chunk l&3), inverse
// permute on the GLOBAL source column (sc), forward permute on the
// ds_read offset (qs). Row groups differ by multiples of 16 so the
// permute term is row-invariant across gA0/gA1 (and all frag rows).

#define GEMM_PREAMBLE                                                        \
    const int tid = threadIdx.x, lane = tid & 63, wave = tid >> 6;           \
    const int wm = (wave >> 1) * 64, wn = (wave & 1) * 64;                   \
    const int fr = lane & 15, q = lane >> 4;                                 \
    const int qs = (q ^ ((fr >> 1) & 3)) * 8;                                \
    const int sr = lane >> 2;                                                \
    const int sc = ((lane & 3) ^ ((lane >> 3) & 3)) * 8;

#define GEMM_LDS                                                             \
    __shared__ alignas(16) f16 As[3][128 * 32];                              \
    __shared__ alignas(16) f16 Bs[3][128 * 32];

// one stage = 4 global_load_lds instructions per thread (16KB/tile).
#define GEMM_STAGE(si, ofs)                                                  \
    lds16(&As[si][wave * 32 * 32], gA0 + (ofs));                             \
    lds16(&As[si][(wave * 32 + 16) * 32], gA1 + (ofs));                      \
    lds16(&Bs[si][wave * 32 * 32], gB0 + (ofs));                             \
    lds16(&Bs[si][(wave * 32 + 16) * 32], gB1 + (ofs));

#define GEMM_MFMA(ri)                                                        \
    {                                                                        \
        f16x8 af[4], bf[4];                                                  \
        _Pragma("unroll")                                                    \
        for (int i = 0; i < 4; ++i)                                          \
            af[i] = *(const f16x8*)&As[ri][(wm + i * 16 + fr) * 32 + qs];    \
        _Pragma("unroll")                                                    \
        for (int j = 0; j < 4; ++j)                                          \
            bf[j] = *(const f16x8*)&Bs[ri][(wn + j * 16 + fr) * 32 + qs];    \
        _Pragma("unroll")                                                    \
        for (int i = 0; i < 4; ++i)                                          \
            _Pragma("unroll")                                                \
            for (int j = 0; j < 4; ++j)                                      \
                acc[i][j] = __builtin_amdgcn_mfma_f32_16x16x32_f16(          \
                    af[i], bf[j], acc[i][j], 0, 0, 0);                       \
    }

// Pipelined K-loop, fully unrolled (KITERS literal) so buffer indices
// t%3 and stage offsets constant-fold. Steady state: wait vmcnt(4)
// [stage t landed; stage t+1 (4 loads) in flight], barrier, issue
// stage t+2, compute tile t. vmcnt drains to 0 only on the final
// iteration. Race safety as verified r4-r6.
#define GEMM_LOOP(KITERS)                                                    \
    GEMM_STAGE(0, 0)                                                         \
    GEMM_STAGE(1, 32)                                                        \
    _Pragma("unroll")                                                        \
    for (int t = 0; t < (KITERS); ++t) {                                     \
        if (t < (KITERS) - 1)                                                \
            asm volatile("s_waitcnt vmcnt(4)" ::: "memory");                 \
        else                                                                 \
            asm volatile("s_waitcnt vmcnt(0)" ::: "memory");                 \
        __builtin_amdgcn_s_barrier();                                        \
        asm volatile("" ::: "memory");                                       \
        if (t + 2 < (KITERS)) { GEMM_STAGE((t + 2) % 3, (t + 2) * 32) }      \
        GEMM_MFMA(t % 3)                                                     \
    }

// shared GEMM1: H1 = silu(Xh @ Ws1), fp16. M=2048 N=4096 K=1024.
__global__ __launch_bounds__(256) void g_shared1(const f16* __restrict__ Xh,
                                                 const f16* __restrict__ Bt,  // [FF][HD]
                                                 f16* __restrict__ H1)
{
    GEMM_LDS
    GEMM_PREAMBLE
    const int m0 = blockIdx.y * 128, n0 = blockIdx.x * 128;
    const f16* gA0 = Xh + (size_t)(m0 + wave * 32 + sr) * HD + sc;
    const f16* gA1 = gA0 + (size_t)16 * HD;
    const f16* gB0 = Bt + (size_t)(n0 + wave * 32 + sr) * HD + sc;
    const f16* gB1 = gB0 + (size_t)16 * HD;

    f32x4 acc[4][4] = {};
    GEMM_LOOP(32)

    #pragma unroll
    for (int i = 0; i < 4; ++i)
        #pragma unroll
        for (int j = 0; j < 4; ++j)
            #pragma unroll
            for (int r = 0; r < 4; ++r) {
                int m = m0 + wm + i * 16 + q * 4 + r;
                int n = n0 + wn + j * 16 + fr;
                float v = acc[i][j][r];
                H1[(size_t)m * FF + n] = (f16)(v / (1.f + expf(-v)));
            }
}

// shared GEMM2: Out += H1 @ Ws2, split-K=4 atomics. M=2048 N=1024 K=4096.
__global__ __launch_bounds__(256) void g_shared2(const f16* __restrict__ H1,
                                                 const f16* __restrict__ Bt,  // [HD][FF]
                                                 float* __restrict__ Out)
{
    GEMM_LDS
    GEMM_PREAMBLE
    const int m0 = blockIdx.y * 128, n0 = blockIdx.x * 128;
    const int kbase = blockIdx.z * (FF / 4);
    const f16* gA0 = H1 + (size_t)(m0 + wave * 32 + sr) * FF + kbase + sc;
    const f16* gA1 = gA0 + (size_t)16 * FF;
    const f16* gB0 = Bt + (size_t)(n0 + wave * 32 + sr) * FF + kbase + sc;
    const f16* gB1 = gB0 + (size_t)16 * FF;

    f32x4 acc[4][4] = {};
    GEMM_LOOP(32)

    #pragma unroll
    for (int i = 0; i < 4; ++i)
        #pragma unroll
        for (int j = 0; j < 4; ++j)
            #pragma unroll
            for (int r = 0; r < 4; ++r) {
                int m = m0 + wm + i * 16 + q * 4 + r;
                int n = n0 + wn + j * 16 + fr;
                atomicAdd(&Out[(size_t)m * HD + n], acc[i][j][r]);
            }
}

// expert GEMM1: Hx[slot] = silu(Xh[rtok[slot]] @ W1[e]) fp16. K=1024 N=512.
// 1-D grid 4096, XCD-residue swizzle: lid = r + 8*(g*64 + k), e = g*8+r,
// k = y*4+x (y<16 covers cnt<=2048, x<4 n-blocks). All blocks of expert
// e share linear-ID residue r mod 8 -> same XCD -> W slice L2-resident.
__global__ __launch_bounds__(256) void g_exp1(const f16* __restrict__ Xh,
                                              const f16* __restrict__ W1t, // [E][M][H]
                                              const int* __restrict__ counts,
                                              const int* __restrict__ offsets,
                                              const int* __restrict__ rtok,
                                              f16* __restrict__ Hx)
{
    const int lid = blockIdx.x;
    const int rres = lid & 7;
    const int t2 = lid >> 3;
    const int k = t2 & 63;
    const int g = t2 >> 6;
    const int e = g * 8 + rres;
    const int cnt = counts[e];
    const int mt = (k >> 2) * 128;
    if (mt >= cnt) return;
    const int off = offsets[e];
    const int n0 = (k & 3) * 128;
    const f16* W = W1t + (size_t)e * MD * HD;

    GEMM_LDS
    GEMM_PREAMBLE

    int rm0 = mt + wave * 32 + sr;
    int rm1 = rm0 + 16;
    int s0 = off + (rm0 < cnt ? rm0 : cnt - 1);
    int s1 = off + (rm1 < cnt ? rm1 : cnt - 1);
    const f16* gA0 = Xh + (size_t)rtok[s0] * HD + sc;
    const f16* gA1 = Xh + (size_t)rtok[s1] * HD + sc;
    const f16* gB0 = W + (size_t)(n0 + wave * 32 + sr) * HD + sc;
    const f16* gB1 = gB0 + (size_t)16 * HD;

    f32x4 acc[4][4] = {};
    GEMM_LOOP(32)

    #pragma unroll
    for (int i = 0; i < 4; ++i)
        #pragma unroll
        for (int j = 0; j < 4; ++j)
            #pragma unroll
            for (int r = 0; r < 4; ++r) {
                int m_in = mt + wm + i * 16 + q * 4 + r;
                if (m_in < cnt) {
                    int n = n0 + wn + j * 16 + fr;
                    float v = acc[i][j][r];
                    Hx[(size_t)(off + m_in) * MD + n] = (f16)(v / (1.f + expf(-v)));
                }
            }
}

// expert GEMM2: Out[t] += w * (Hx @ W2[e]). K=512 N=1024, atomic scatter.
// 1-D grid 8192, same XCD-residue swizzle: lid = r + 8*(g*128 + k),
// e = g*8+r, k = y*8+x (y<16, x<8 n-blocks).
__global__ __launch_bounds__(256) void g_exp2(const f16* __restrict__ Hx,
                                              const f16* __restrict__ W2t, // [E][H][M]
                                              const int* __restrict__ counts,
                                              const int* __restrict__ offsets,
                                              const int* __restrict__ rtok,
                                              const float* __restrict__ rw,
                                              float* __restrict__ Out)
{
    const int lid = blockIdx.x;
    const int rres = lid & 7;
    const int t2 = lid >> 3;
    const int k = t2 & 127;
    const int g = t2 >> 7;
    const int e = g * 8 + rres;
    const int cnt = counts[e];
    const int mt = (k >> 3) * 128;
    if (mt >= cnt) return;
    const int off = offsets[e];
    const int n0 = (k & 7) * 128;
    const f16* W = W2t + (size_t)e * HD * MD;

    GEMM_LDS
    GEMM_PREAMBLE

    // A rows are packed slots; Hx pad rows (128) make OOB reads safe
    // (masked at C).
    const f16* gA0 = Hx + (size_t)(off + mt + wave * 32 + sr) * MD + sc;
    const f16* gA1 = gA0 + (size_t)16 * MD;
    const f16* gB0 = W + (size_t)(n0 + wave * 32 + sr) * MD + sc;
    const f16* gB1 = gB0 + (size_t)16 * MD;

    f32x4 acc[4][4] = {};
    GEMM_LOOP(16)

    #pragma unroll
    for (int i = 0; i < 4; ++i)
        #pragma unroll
        for (int r = 0; r < 4; ++r) {
            int m_in = mt + wm + i * 16 + q * 4 + r;
            if (m_in < cnt) {
                int slot = off + m_in;
                int t = rtok[slot];
                float w = rw[slot];
                float* orow = Out + (size_t)t * HD + n0 + wn + fr;
                #pragma unroll
                for (int j = 0; j < 4; ++j)
                    atomicAdd(&orow[j * 16], w * acc[i][j][r]);
            }
        }
}

// ------------------------------------------------------------------
extern "C" void kernel_launch(void* const* d_in, const int* in_sizes, int n_in,
                              void* d_out, int out_size, void* d_ws, size_t ws_size,
                              hipStream_t stream)
{
    (void)in_sizes; (void)n_in; (void)out_size; (void)ws_size;
    const float* X   = (const float*)d_in[0];
    const float* Ws1 = (const float*)d_in[1];
    const float* Ws2 = (const float*)d_in[2];
    const float* Wg  = (const float*)d_in[3];
    const float* W1  = (const float*)d_in[4];
    const float* W2  = (const float*)d_in[5];
    float* out = (float*)d_out;
    float* logits = out + (size_t)NT * HD;

    char* ws = (char*)d_ws;
    f16*   h1       = (f16*)(ws + O_H1);
    f16*   hx       = (f16*)(ws + O_HX);
    int*   topk_idx = (int*)(ws + O_TOPKI);
    float* topk_w   = (float*)(ws + O_TOPKW);
    int*   counts   = (int*)(ws + O_COUNTS);
    int*   cursors  = (int*)(ws + O_CURSORS);
    int*   offsets  = (int*)(ws + O_OFFSETS);
    int*   rtok     = (int*)(ws + O_RTOK);
    float* rwt      = (float*)(ws + O_RW);
    f16*   xh       = (f16*)(ws + O_XH);
    f16*   w1t      = (f16*)(ws + O_W1T);
    f16*   w2t      = (f16*)(ws + O_W2T);
    f16*   ws1t     = (f16*)(ws + O_WS1T);
    f16*   ws2t     = (f16*)(ws + O_WS2T);

    hipMemsetAsync(counts, 0, 512, stream);   // counts + cursors

    k_router<<<NT / 4, 256, 0, stream>>>(X, Wg, logits);
    k_topk<<<NT, 64, 0, stream>>>(logits, topk_idx, topk_w, counts);
    k_scan<<<1, 64, 0, stream>>>(counts, offsets);
    k_route<<<NT * TOPK / 256, 256, 0, stream>>>(topk_idx, topk_w, offsets, cursors, rtok, rwt);

    // conversion pre-pass
    k_cvt_x<<<NT * HD / 1024, 256, 0, stream>>>(X, xh);
    k_cvt_t<<<dim3(FF / 64, HD / 64, 1), 256, 0, stream>>>(Ws1, ws1t, HD, FF);
    k_cvt_t<<<dim3(HD / 64, FF / 64, 1), 256, 0, stream>>>(Ws2, ws2t, FF, HD);
    k_cvt_t<<<dim3(MD / 64, HD / 64, NE), 256, 0, stream>>>(W1, w1t, HD, MD);
    k_cvt_t<<<dim3(HD / 64, MD / 64, NE), 256, 0, stream>>>(W2, w2t, MD, HD);
    hipMemsetAsync(out, 0, (size_t)NT * HD * 4, stream);

    g_shared1<<<dim3(FF / 128, NT / 128), 256, 0, stream>>>(xh, ws1t, h1);
    g_shared2<<<dim3(HD / 128, NT / 128, 4), 256, 0, stream>>>(h1, ws2t, out);
    g_exp1<<<4096, 256, 0, stream>>>(xh, w1t, counts, offsets, rtok, hx);
    g_exp2<<<8192, 256, 0, stream>>>(hx, w2t, counts, offsets, rtok, rwt, out);
}

// Round 5
// 612.424 us; speedup vs baseline: 1.1361x; 1.0618x over previous
//
#include <hip/hip_runtime.h>
#include <cmath>

// DeepSeek MoE layer, MI355X (gfx950). Round 8.
// B=2,S=1024 -> T=2048 tokens. H=1024, FF=4096, E=64, K=8, M=512.
//
// Round-8 changes vs round 7 (g_exp2 = atomic-scatter kernel with a GEMM
// attached: 65.5 MB atomic RMW WRITE_SIZE, 16.8M scalar atomicAdds per
// dispatch; FETCH halved by XCD swizzle but time unmoved -> epilogue
// bound, not fetch/compute):
//  - g_exp2 now stores UNWEIGHTED y rows to Hy[slot][H] as plain
//    coalesced fp16 stores (no atomics, no rw/rtok in the kernel).
//  - g_shared2 stores split-K partials to S2p[z][T][H] fp32, plain
//    stores (no atomics).
//  - k_route also writes the token->slot inverse map tslot[t*8+k].
//  - New k_gather: Out[t][h] = sum_z S2p[z][t][h]
//      + sum_k topk_w[t,k] * Hy[tslot[t,k]][h].  Pure streaming
//    (~75 MB total), replaces ~96 MB of serialized atomic RMW.
//  - hipMemsetAsync(out) dropped (gather fully overwrites Out).
//  - GEMM core (128x128, counted-vmcnt 3-buffer pipeline, LDS chunk-XOR
//    swizzle, XCD-residue expert grids) unchanged from r7 (verified).

typedef _Float16 f16;
typedef __attribute__((ext_vector_type(4))) _Float16 f16x4;
typedef __attribute__((ext_vector_type(8))) _Float16 f16x8;
typedef __attribute__((ext_vector_type(4))) float f32x4;

#define NT 2048      // tokens
#define HD 1024      // hidden
#define FF 4096      // shared intermediate
#define NE 64        // experts
#define TOPK 8
#define MD 512       // moe intermediate

// ---- workspace layout (bytes) ----
constexpr size_t SZ_H1 = (size_t)NT * FF * 2;                // fp16 [2048][4096]
constexpr size_t SZ_HX = (size_t)(NT * TOPK + 128) * MD * 2; // fp16 [16512][512]
constexpr size_t O_H1 = 0;
constexpr size_t O_HX = O_H1 + SZ_H1;
constexpr size_t O_TOPKI = O_HX + SZ_HX;
constexpr size_t O_TOPKW = O_TOPKI + (size_t)NT * TOPK * 4;
constexpr size_t O_COUNTS = O_TOPKW + (size_t)NT * TOPK * 4;
constexpr size_t O_CURSORS = O_COUNTS + 256;
constexpr size_t O_OFFSETS = O_CURSORS + 256;
constexpr size_t O_RTOK = O_OFFSETS + 256;
constexpr size_t O_RW = O_RTOK + (size_t)NT * TOPK * 4;
constexpr size_t O_TSLOT = O_RW + (size_t)NT * TOPK * 4;
constexpr size_t O_XH = ((O_TSLOT + (size_t)NT * TOPK * 4 + 255) / 256) * 256;
constexpr size_t O_W1T = O_XH + (size_t)NT * HD * 2;         // fp16 [E][M][H]
constexpr size_t O_W2T = O_W1T + (size_t)NE * HD * MD * 2;   // fp16 [E][H][M]
constexpr size_t O_WS1T = O_W2T + (size_t)NE * MD * HD * 2;  // fp16 [FF][H]
constexpr size_t O_WS2T = O_WS1T + (size_t)HD * FF * 2;      // fp16 [H][FF]
constexpr size_t O_HY = O_WS2T + (size_t)FF * HD * 2;        // fp16 [16512][1024]
constexpr size_t SZ_HY = (size_t)(NT * TOPK + 128) * HD * 2;
constexpr size_t O_S2P = O_HY + SZ_HY;                       // fp32 [4][2048][1024]
constexpr size_t WS_NEEDED = O_S2P + (size_t)4 * NT * HD * 4; // ~256 MB

// async global->LDS, 16B per lane; lane i lands at ldsbase + i*16.
__device__ __forceinline__ void lds16(void* l, const void* g) {
    __builtin_amdgcn_global_load_lds(
        (const __attribute__((address_space(1))) void*)g,
        (__attribute__((address_space(3))) void*)l, 16, 0, 0);
}

// ------------------------------------------------------------------
// router: logits[t][e] = dot(x[t], Wg[:,e]) in fp32 (must match numpy top-k).
__global__ __launch_bounds__(256) void k_router(const float* __restrict__ X,
                                                const float* __restrict__ Wg,
                                                float* __restrict__ logits)
{
    __shared__ float xs[4][HD];
    const int tid = threadIdx.x;
    const int t0 = blockIdx.x * 4;
    #pragma unroll
    for (int i = 0; i < 4; ++i) {
        int f4 = tid + i * 256;
        int row = f4 >> 8;
        int col = (f4 & 255) * 4;
        *(float4*)&xs[row][col] = *(const float4*)&X[(t0 + row) * HD + col];
    }
    __syncthreads();
    const int e = tid & 63, tok = tid >> 6;
    float a0 = 0.f, a1 = 0.f, a2 = 0.f, a3 = 0.f;
    const float* xr = xs[tok];
    for (int h = 0; h < HD; h += 4) {
        a0 += xr[h + 0] * Wg[(h + 0) * NE + e];
        a1 += xr[h + 1] * Wg[(h + 1) * NE + e];
        a2 += xr[h + 2] * Wg[(h + 2) * NE + e];
        a3 += xr[h + 3] * Wg[(h + 3) * NE + e];
    }
    logits[(t0 + tok) * NE + e] = (a0 + a1) + (a2 + a3);
}

// top-8 + softmax per token; one wave per token; tie-break lower index.
__global__ __launch_bounds__(64) void k_topk(const float* __restrict__ logits,
                                             int* __restrict__ topk_idx,
                                             float* __restrict__ topk_w,
                                             int* __restrict__ counts)
{
    const int t = blockIdx.x;
    const int lane = threadIdx.x;
    __shared__ float sval[TOPK];
    __shared__ int sidx[TOPK];
    float cur = logits[t * NE + lane];
    for (int it = 0; it < TOPK; ++it) {
        float v = cur; int id = lane;
        #pragma unroll
        for (int off = 32; off > 0; off >>= 1) {
            float ov = __shfl_xor(v, off, 64);
            int   oi = __shfl_xor(id, off, 64);
            if (ov > v || (ov == v && oi < id)) { v = ov; id = oi; }
        }
        if (lane == 0) { sval[it] = v; sidx[it] = id; }
        if (lane == id) cur = -INFINITY;
    }
    __syncthreads();
    if (lane < TOPK) {
        float m = sval[0];
        float denom = 0.f;
        #pragma unroll
        for (int j = 0; j < TOPK; ++j) denom += expf(sval[j] - m);
        float w = expf(sval[lane] - m) / denom;
        int e = sidx[lane];
        topk_idx[t * TOPK + lane] = e;
        topk_w[t * TOPK + lane] = w;
        atomicAdd(&counts[e], 1);
    }
}

__global__ void k_scan(const int* __restrict__ counts, int* __restrict__ offsets)
{
    if (threadIdx.x == 0) {
        int run = 0;
        for (int e = 0; e < NE; ++e) { offsets[e] = run; run += counts[e]; }
    }
}

// routes token-expert pairs to packed slots; also records the inverse
// map tslot[t*8+k] = slot, used by the gather epilogue.
__global__ __launch_bounds__(256) void k_route(const int* __restrict__ topk_idx,
                                               const float* __restrict__ topk_w,
                                               const int* __restrict__ offsets,
                                               int* __restrict__ cursors,
                                               int* __restrict__ rtok,
                                               int* __restrict__ tslot)
{
    int i = blockIdx.x * 256 + threadIdx.x;
    int e = topk_idx[i];
    int pos = atomicAdd(&cursors[e], 1);
    int slot = offsets[e] + pos;
    rtok[slot] = i >> 3;
    tslot[i] = slot;
}

// ------------------------------------------------------------------
// conversion pre-pass
__global__ __launch_bounds__(256) void k_cvt_x(const float* __restrict__ X,
                                               f16* __restrict__ Xh)
{
    int i = blockIdx.x * 256 + threadIdx.x;
    float4 v = ((const float4*)X)[i];
    f16x4 h = { (f16)v.x, (f16)v.y, (f16)v.z, (f16)v.w };
    ((f16x4*)Xh)[i] = h;
}

// fp32 [K][N] -> fp16 [N][K] (transpose), batched over blockIdx.z.
__global__ __launch_bounds__(256) void k_cvt_t(const float* __restrict__ src,
                                               f16* __restrict__ dst,
                                               int K, int N)
{
    const size_t bofs = (size_t)blockIdx.z * K * N;
    src += bofs; dst += bofs;
    const int n0 = blockIdx.x * 64, k0 = blockIdx.y * 64;
    __shared__ f16 t[64][68];
    const int tid = threadIdx.x;
    #pragma unroll
    for (int i = 0; i < 4; ++i) {
        int idx = tid + i * 256;
        int r = idx >> 4, c4 = (idx & 15) * 4;
        float4 v = *(const float4*)&src[(size_t)(k0 + r) * N + n0 + c4];
        f16x4 h = { (f16)v.x, (f16)v.y, (f16)v.z, (f16)v.w };
        *(f16x4*)&t[r][c4] = h;
    }
    __syncthreads();
    #pragma unroll
    for (int i = 0; i < 4; ++i) {
        int idx = tid + i * 256;
        int nr = idx >> 4, kc = (idx & 15) * 4;
        f16x4 o = { t[kc][nr], t[kc + 1][nr], t[kc + 2][nr], t[kc + 3][nr] };
        *(f16x4*)&dst[(size_t)(n0 + nr) * K + k0 + kc] = o;
    }
}

// ------------------------------------------------------------------
// GEMM core: 128x128 tile, BK=32, 4 waves (2 M-halves x 2 N-halves),
// wave = 64x64 = acc[4][4]. 3-buffer depth-2 pipeline, counted vmcnt,
// raw s_barrier (one per iter). LDS/buffer: As 128x32, Bs 128x32 (16KB).
// Frag mapping (verified r0-r7): A[m=fr][k=q*8+j], B[n=fr][k=q*8+j],
// C/D col=fr, row=q*4+reg.
//
// LDS swizzle (verified r6/r7: SQ_LDS_BANK_CONFLICT = 0): logical chunk
// c (of 4x16B per row) stored at physical chunk c^((row>>1)&3). Linear
// global_load_lds dest, inverse permute on the GLOBAL source column
// (sc), forward permute on the ds_read offset (qs).

#define GEMM_PREAMBLE                                                        \
    const int tid = threadIdx.x, lane = tid & 63, wave = tid >> 6;           \
    const int wm = (wave >> 1) * 64, wn = (wave & 1) * 64;                   \
    const int fr = lane & 15, q = lane >> 4;                                 \
    const int qs = (q ^ ((fr >> 1) & 3)) * 8;                                \
    const int sr = lane >> 2;                                                \
    const int sc = ((lane & 3) ^ ((lane >> 3) & 3)) * 8;

#define GEMM_LDS                                                             \
    __shared__ alignas(16) f16 As[3][128 * 32];                              \
    __shared__ alignas(16) f16 Bs[3][128 * 32];

// one stage = 4 global_load_lds instructions per thread (16KB/tile).
#define GEMM_STAGE(si, ofs)                                                  \
    lds16(&As[si][wave * 32 * 32], gA0 + (ofs));                             \
    lds16(&As[si][(wave * 32 + 16) * 32], gA1 + (ofs));                      \
    lds16(&Bs[si][wave * 32 * 32], gB0 + (ofs));                             \
    lds16(&Bs[si][(wave * 32 + 16) * 32], gB1 + (ofs));

#define GEMM_MFMA(ri)                                                        \
    {                                                                        \
        f16x8 af[4], bf[4];                                                  \
        _Pragma("unroll")                                                    \
        for (int i = 0; i < 4; ++i)                                          \
            af[i] = *(const f16x8*)&As[ri][(wm + i * 16 + fr) * 32 + qs];    \
        _Pragma("unroll")                                                    \
        for (int j = 0; j < 4; ++j)                                          \
            bf[j] = *(const f16x8*)&Bs[ri][(wn + j * 16 + fr) * 32 + qs];    \
        _Pragma("unroll")                                                    \
        for (int i = 0; i < 4; ++i)                                          \
            _Pragma("unroll")                                                \
            for (int j = 0; j < 4; ++j)                                      \
                acc[i][j] = __builtin_amdgcn_mfma_f32_16x16x32_f16(          \
                    af[i], bf[j], acc[i][j], 0, 0, 0);                       \
    }

// Pipelined K-loop, fully unrolled (KITERS literal) so buffer indices
// t%3 and stage offsets constant-fold. Steady state: wait vmcnt(4)
// [stage t landed; stage t+1 (4 loads) in flight], barrier, issue
// stage t+2, compute tile t. vmcnt drains to 0 only on the final
// iteration. Race safety as verified r4-r7.
#define GEMM_LOOP(KITERS)                                                    \
    GEMM_STAGE(0, 0)                                                         \
    GEMM_STAGE(1, 32)                                                        \
    _Pragma("unroll")                                                        \
    for (int t = 0; t < (KITERS); ++t) {                                     \
        if (t < (KITERS) - 1)                                                \
            asm volatile("s_waitcnt vmcnt(4)" ::: "memory");                 \
        else                                                                 \
            asm volatile("s_waitcnt vmcnt(0)" ::: "memory");                 \
        __builtin_amdgcn_s_barrier();                                        \
        asm volatile("" ::: "memory");                                       \
        if (t + 2 < (KITERS)) { GEMM_STAGE((t + 2) % 3, (t + 2) * 32) }      \
        GEMM_MFMA(t % 3)                                                     \
    }

// shared GEMM1: H1 = silu(Xh @ Ws1), fp16. M=2048 N=4096 K=1024.
__global__ __launch_bounds__(256) void g_shared1(const f16* __restrict__ Xh,
                                                 const f16* __restrict__ Bt,  // [FF][HD]
                                                 f16* __restrict__ H1)
{
    GEMM_LDS
    GEMM_PREAMBLE
    const int m0 = blockIdx.y * 128, n0 = blockIdx.x * 128;
    const f16* gA0 = Xh + (size_t)(m0 + wave * 32 + sr) * HD + sc;
    const f16* gA1 = gA0 + (size_t)16 * HD;
    const f16* gB0 = Bt + (size_t)(n0 + wave * 32 + sr) * HD + sc;
    const f16* gB1 = gB0 + (size_t)16 * HD;

    f32x4 acc[4][4] = {};
    GEMM_LOOP(32)

    #pragma unroll
    for (int i = 0; i < 4; ++i)
        #pragma unroll
        for (int j = 0; j < 4; ++j)
            #pragma unroll
            for (int r = 0; r < 4; ++r) {
                int m = m0 + wm + i * 16 + q * 4 + r;
                int n = n0 + wn + j * 16 + fr;
                float v = acc[i][j][r];
                H1[(size_t)m * FF + n] = (f16)(v / (1.f + expf(-v)));
            }
}

// shared GEMM2: S2p[z] = H1 @ Ws2 K-slice, fp32 plain stores (no atomics).
// M=2048 N=1024 K=4096 split-K=4.
__global__ __launch_bounds__(256) void g_shared2(const f16* __restrict__ H1,
                                                 const f16* __restrict__ Bt,  // [HD][FF]
                                                 float* __restrict__ S2p)
{
    GEMM_LDS
    GEMM_PREAMBLE
    const int m0 = blockIdx.y * 128, n0 = blockIdx.x * 128;
    const int kbase = blockIdx.z * (FF / 4);
    float* P = S2p + (size_t)blockIdx.z * NT * HD;
    const f16* gA0 = H1 + (size_t)(m0 + wave * 32 + sr) * FF + kbase + sc;
    const f16* gA1 = gA0 + (size_t)16 * FF;
    const f16* gB0 = Bt + (size_t)(n0 + wave * 32 + sr) * FF + kbase + sc;
    const f16* gB1 = gB0 + (size_t)16 * FF;

    f32x4 acc[4][4] = {};
    GEMM_LOOP(32)

    #pragma unroll
    for (int i = 0; i < 4; ++i)
        #pragma unroll
        for (int j = 0; j < 4; ++j)
            #pragma unroll
            for (int r = 0; r < 4; ++r) {
                int m = m0 + wm + i * 16 + q * 4 + r;
                int n = n0 + wn + j * 16 + fr;
                P[(size_t)m * HD + n] = acc[i][j][r];
            }
}

// expert GEMM1: Hx[slot] = silu(Xh[rtok[slot]] @ W1[e]) fp16. K=1024 N=512.
// 1-D grid 4096, XCD-residue swizzle: lid = r + 8*(g*64 + k), e = g*8+r,
// k = y*4+x (y<16 covers cnt<=2048, x<4 n-blocks). All blocks of expert
// e share linear-ID residue r mod 8 -> same XCD -> W slice L2-resident.
__global__ __launch_bounds__(256) void g_exp1(const f16* __restrict__ Xh,
                                              const f16* __restrict__ W1t, // [E][M][H]
                                              const int* __restrict__ counts,
                                              const int* __restrict__ offsets,
                                              const int* __restrict__ rtok,
                                              f16* __restrict__ Hx)
{
    const int lid = blockIdx.x;
    const int rres = lid & 7;
    const int t2 = lid >> 3;
    const int k = t2 & 63;
    const int g = t2 >> 6;
    const int e = g * 8 + rres;
    const int cnt = counts[e];
    const int mt = (k >> 2) * 128;
    if (mt >= cnt) return;
    const int off = offsets[e];
    const int n0 = (k & 3) * 128;
    const f16* W = W1t + (size_t)e * MD * HD;

    GEMM_LDS
    GEMM_PREAMBLE

    int rm0 = mt + wave * 32 + sr;
    int rm1 = rm0 + 16;
    int s0 = off + (rm0 < cnt ? rm0 : cnt - 1);
    int s1 = off + (rm1 < cnt ? rm1 : cnt - 1);
    const f16* gA0 = Xh + (size_t)rtok[s0] * HD + sc;
    const f16* gA1 = Xh + (size_t)rtok[s1] * HD + sc;
    const f16* gB0 = W + (size_t)(n0 + wave * 32 + sr) * HD + sc;
    const f16* gB1 = gB0 + (size_t)16 * HD;

    f32x4 acc[4][4] = {};
    GEMM_LOOP(32)

    #pragma unroll
    for (int i = 0; i < 4; ++i)
        #pragma unroll
        for (int j = 0; j < 4; ++j)
            #pragma unroll
            for (int r = 0; r < 4; ++r) {
                int m_in = mt + wm + i * 16 + q * 4 + r;
                if (m_in < cnt) {
                    int n = n0 + wn + j * 16 + fr;
                    float v = acc[i][j][r];
                    Hx[(size_t)(off + m_in) * MD + n] = (f16)(v / (1.f + expf(-v)));
                }
            }
}

// expert GEMM2: Hy[slot] = Hx[slot] @ W2[e], fp16 plain stores (no
// atomics, no weights -- the gather applies them). K=512 N=1024.
// 1-D grid 8192, same XCD-residue swizzle: lid = r + 8*(g*128 + k),
// e = g*8+r, k = y*8+x (y<16, x<8 n-blocks).
__global__ __launch_bounds__(256) void g_exp2(const f16* __restrict__ Hx,
                                              const f16* __restrict__ W2t, // [E][H][M]
                                              const int* __restrict__ counts,
                                              const int* __restrict__ offsets,
                                              f16* __restrict__ Hy)
{
    const int lid = blockIdx.x;
    const int rres = lid & 7;
    const int t2 = lid >> 3;
    const int k = t2 & 127;
    const int g = t2 >> 7;
    const int e = g * 8 + rres;
    const int cnt = counts[e];
    const int mt = (k >> 3) * 128;
    if (mt >= cnt) return;
    const int off = offsets[e];
    const int n0 = (k & 7) * 128;
    const f16* W = W2t + (size_t)e * HD * MD;

    GEMM_LDS
    GEMM_PREAMBLE

    // A rows are packed slots; Hx pad rows (128) make OOB reads safe
    // (masked at C).
    const f16* gA0 = Hx + (size_t)(off + mt + wave * 32 + sr) * MD + sc;
    const f16* gA1 = gA0 + (size_t)16 * MD;
    const f16* gB0 = W + (size_t)(n0 + wave * 32 + sr) * MD + sc;
    const f16* gB1 = gB0 + (size_t)16 * MD;

    f32x4 acc[4][4] = {};
    GEMM_LOOP(16)

    #pragma unroll
    for (int i = 0; i < 4; ++i)
        #pragma unroll
        for (int j = 0; j < 4; ++j)
            #pragma unroll
            for (int r = 0; r < 4; ++r) {
                int m_in = mt + wm + i * 16 + q * 4 + r;
                if (m_in < cnt) {
                    int n = n0 + wn + j * 16 + fr;
                    Hy[(size_t)(off + m_in) * HD + n] = (f16)acc[i][j][r];
                }
            }
}

// gather epilogue: Out[t][h] = sum_z S2p[z][t][h]
//                            + sum_k topk_w[t,k] * Hy[tslot[t,k]][h].
// One block per token, 256 threads x float4. Pure streaming (~75 MB).
__global__ __launch_bounds__(256) void k_gather(const float* __restrict__ S2p,
                                                const f16* __restrict__ Hy,
                                                const int* __restrict__ tslot,
                                                const float* __restrict__ tw,
                                                float* __restrict__ Out)
{
    const int t = blockIdx.x;
    const int tid = threadIdx.x;
    __shared__ int ss[TOPK];
    __shared__ float sw[TOPK];
    if (tid < TOPK) {
        ss[tid] = tslot[t * TOPK + tid];
        sw[tid] = tw[t * TOPK + tid];
    }
    __syncthreads();
    const int h = tid * 4;
    float4 a = *(const float4*)&S2p[(size_t)t * HD + h];
    #pragma unroll
    for (int z = 1; z < 4; ++z) {
        float4 b = *(const float4*)&S2p[(size_t)z * NT * HD + (size_t)t * HD + h];
        a.x += b.x; a.y += b.y; a.z += b.z; a.w += b.w;
    }
    #pragma unroll
    for (int kk = 0; kk < TOPK; ++kk) {
        f16x4 y = *(const f16x4*)&Hy[(size_t)ss[kk] * HD + h];
        float w = sw[kk];
        a.x += w * (float)y[0];
        a.y += w * (float)y[1];
        a.z += w * (float)y[2];
        a.w += w * (float)y[3];
    }
    *(float4*)&Out[(size_t)t * HD + h] = a;
}

// ------------------------------------------------------------------
extern "C" void kernel_launch(void* const* d_in, const int* in_sizes, int n_in,
                              void* d_out, int out_size, void* d_ws, size_t ws_size,
                              hipStream_t stream)
{
    (void)in_sizes; (void)n_in; (void)out_size; (void)ws_size;
    const float* X   = (const float*)d_in[0];
    const float* Ws1 = (const float*)d_in[1];
    const float* Ws2 = (const float*)d_in[2];
    const float* Wg  = (const float*)d_in[3];
    const float* W1  = (const float*)d_in[4];
    const float* W2  = (const float*)d_in[5];
    float* out = (float*)d_out;
    float* logits = out + (size_t)NT * HD;

    char* ws = (char*)d_ws;
    f16*   h1       = (f16*)(ws + O_H1);
    f16*   hx       = (f16*)(ws + O_HX);
    int*   topk_idx = (int*)(ws + O_TOPKI);
    float* topk_w   = (float*)(ws + O_TOPKW);
    int*   counts   = (int*)(ws + O_COUNTS);
    int*   cursors  = (int*)(ws + O_CURSORS);
    int*   offsets  = (int*)(ws + O_OFFSETS);
    int*   rtok     = (int*)(ws + O_RTOK);
    int*   tslot    = (int*)(ws + O_TSLOT);
    f16*   xh       = (f16*)(ws + O_XH);
    f16*   w1t      = (f16*)(ws + O_W1T);
    f16*   w2t      = (f16*)(ws + O_W2T);
    f16*   ws1t     = (f16*)(ws + O_WS1T);
    f16*   ws2t     = (f16*)(ws + O_WS2T);
    f16*   hy       = (f16*)(ws + O_HY);
    float* s2p      = (float*)(ws + O_S2P);

    hipMemsetAsync(counts, 0, 512, stream);   // counts + cursors

    k_router<<<NT / 4, 256, 0, stream>>>(X, Wg, logits);
    k_topk<<<NT, 64, 0, stream>>>(logits, topk_idx, topk_w, counts);
    k_scan<<<1, 64, 0, stream>>>(counts, offsets);
    k_route<<<NT * TOPK / 256, 256, 0, stream>>>(topk_idx, topk_w, offsets, cursors, rtok, tslot);

    // conversion pre-pass
    k_cvt_x<<<NT * HD / 1024, 256, 0, stream>>>(X, xh);
    k_cvt_t<<<dim3(FF / 64, HD / 64, 1), 256, 0, stream>>>(Ws1, ws1t, HD, FF);
    k_cvt_t<<<dim3(HD / 64, FF / 64, 1), 256, 0, stream>>>(Ws2, ws2t, FF, HD);
    k_cvt_t<<<dim3(MD / 64, HD / 64, NE), 256, 0, stream>>>(W1, w1t, HD, MD);
    k_cvt_t<<<dim3(HD / 64, MD / 64, NE), 256, 0, stream>>>(W2, w2t, MD, HD);

    g_shared1<<<dim3(FF / 128, NT / 128), 256, 0, stream>>>(xh, ws1t, h1);
    g_shared2<<<dim3(HD / 128, NT / 128, 4), 256, 0, stream>>>(h1, ws2t, s2p);
    g_exp1<<<4096, 256, 0, stream>>>(xh, w1t, counts, offsets, rtok, hx);
    g_exp2<<<8192, 256, 0, stream>>>(hx, w2t, counts, offsets, hy);
    k_gather<<<NT, 256, 0, stream>>>(s2p, hy, tslot, topk_w, out);
}

// Round 7
// 536.662 us; speedup vs baseline: 1.2964x; 1.1412x over previous
//
#include <hip/hip_runtime.h>
#include <cmath>

// DeepSeek MoE layer, MI355X (gfx950). Round 9 (resubmit: round-9 bench
// died on container acquisition, not on the kernel — no pytest/profile
// signal was produced; kernel re-audited for barrier/OOB/swizzle/wait
// hazards, none found).
// B=2,S=1024 -> T=2048 tokens. H=1024, FF=4096, E=64, K=8, M=512.
//
// Round-9 changes vs round 8 (profile showed: harness re-poison fill
// = 77us fixed floor; W1/W2 cvt_t passes = ~65us of 402MB traffic redone
// every iteration because re-poison wipes cached conversions; GEMMs
// pinned ~10% MfmaUtil across 6 schedule variants):
//  - g_exp1/g_exp2 consume W1/W2 DIRECTLY in fp32: the separate
//    transpose-convert passes are deleted. B-staging becomes
//    reg-staged: each lane gathers a 16-deep k-column of W
//    (16x global_load_dword, coalesced 128B along n), converts with
//    RNE casts (same numerics as the old cvt pass), and ds_writes
//    f16x8 chunks with the T2 XOR swizzle applied on the WRITE address
//    (reg path is free of global_load_lds linearity; reads keep qs).
//  - Pipeline: issue stage t+2 (A lds16 + B reg-loads) after barrier t;
//    vmcnt(0) at t+1 drains exactly that batch (1-iter cover; B is
//    XCD-L2-homed ~200cy). Explicit lgkmcnt(0) before each barrier
//    publishes the ds_writes. 3-buffer rotation as verified r6-r8.
//  - A path, shared GEMMs, router/topk/route/gather unchanged.

typedef _Float16 f16;
typedef __attribute__((ext_vector_type(4))) _Float16 f16x4;
typedef __attribute__((ext_vector_type(8))) _Float16 f16x8;
typedef __attribute__((ext_vector_type(4))) float f32x4;

#define NT 2048      // tokens
#define HD 1024      // hidden
#define FF 4096      // shared intermediate
#define NE 64        // experts
#define TOPK 8
#define MD 512       // moe intermediate

// ---- workspace layout (bytes) ----
constexpr size_t SZ_H1 = (size_t)NT * FF * 2;                // fp16 [2048][4096]
constexpr size_t SZ_HX = (size_t)(NT * TOPK + 128) * MD * 2; // fp16 [16512][512]
constexpr size_t O_H1 = 0;
constexpr size_t O_HX = O_H1 + SZ_H1;
constexpr size_t O_TOPKI = O_HX + SZ_HX;
constexpr size_t O_TOPKW = O_TOPKI + (size_t)NT * TOPK * 4;
constexpr size_t O_COUNTS = O_TOPKW + (size_t)NT * TOPK * 4;
constexpr size_t O_CURSORS = O_COUNTS + 256;
constexpr size_t O_OFFSETS = O_CURSORS + 256;
constexpr size_t O_RTOK = O_OFFSETS + 256;
constexpr size_t O_TSLOT = O_RTOK + (size_t)NT * TOPK * 4;
constexpr size_t O_XH = ((O_TSLOT + (size_t)NT * TOPK * 4 + 255) / 256) * 256;
constexpr size_t O_WS1T = O_XH + (size_t)NT * HD * 2;        // fp16 [FF][H]
constexpr size_t O_WS2T = O_WS1T + (size_t)HD * FF * 2;      // fp16 [H][FF]
constexpr size_t O_HY = O_WS2T + (size_t)FF * HD * 2;        // fp16 [16512][1024]
constexpr size_t SZ_HY = (size_t)(NT * TOPK + 128) * HD * 2;
constexpr size_t O_S2P = O_HY + SZ_HY;                       // fp32 [4][2048][1024]
constexpr size_t WS_NEEDED = O_S2P + (size_t)4 * NT * HD * 4;

// async global->LDS, 16B per lane; lane i lands at ldsbase + i*16.
__device__ __forceinline__ void lds16(void* l, const void* g) {
    __builtin_amdgcn_global_load_lds(
        (const __attribute__((address_space(1))) void*)g,
        (__attribute__((address_space(3))) void*)l, 16, 0, 0);
}

// ------------------------------------------------------------------
// router: logits[t][e] = dot(x[t], Wg[:,e]) in fp32 (must match numpy top-k).
__global__ __launch_bounds__(256) void k_router(const float* __restrict__ X,
                                                const float* __restrict__ Wg,
                                                float* __restrict__ logits)
{
    __shared__ float xs[4][HD];
    const int tid = threadIdx.x;
    const int t0 = blockIdx.x * 4;
    #pragma unroll
    for (int i = 0; i < 4; ++i) {
        int f4 = tid + i * 256;
        int row = f4 >> 8;
        int col = (f4 & 255) * 4;
        *(float4*)&xs[row][col] = *(const float4*)&X[(t0 + row) * HD + col];
    }
    __syncthreads();
    const int e = tid & 63, tok = tid >> 6;
    float a0 = 0.f, a1 = 0.f, a2 = 0.f, a3 = 0.f;
    const float* xr = xs[tok];
    for (int h = 0; h < HD; h += 4) {
        a0 += xr[h + 0] * Wg[(h + 0) * NE + e];
        a1 += xr[h + 1] * Wg[(h + 1) * NE + e];
        a2 += xr[h + 2] * Wg[(h + 2) * NE + e];
        a3 += xr[h + 3] * Wg[(h + 3) * NE + e];
    }
    logits[(t0 + tok) * NE + e] = (a0 + a1) + (a2 + a3);
}

// top-8 + softmax per token; one wave per token; tie-break lower index.
__global__ __launch_bounds__(64) void k_topk(const float* __restrict__ logits,
                                             int* __restrict__ topk_idx,
                                             float* __restrict__ topk_w,
                                             int* __restrict__ counts)
{
    const int t = blockIdx.x;
    const int lane = threadIdx.x;
    __shared__ float sval[TOPK];
    __shared__ int sidx[TOPK];
    float cur = logits[t * NE + lane];
    for (int it = 0; it < TOPK; ++it) {
        float v = cur; int id = lane;
        #pragma unroll
        for (int off = 32; off > 0; off >>= 1) {
            float ov = __shfl_xor(v, off, 64);
            int   oi = __shfl_xor(id, off, 64);
            if (ov > v || (ov == v && oi < id)) { v = ov; id = oi; }
        }
        if (lane == 0) { sval[it] = v; sidx[it] = id; }
        if (lane == id) cur = -INFINITY;
    }
    __syncthreads();
    if (lane < TOPK) {
        float m = sval[0];
        float denom = 0.f;
        #pragma unroll
        for (int j = 0; j < TOPK; ++j) denom += expf(sval[j] - m);
        float w = expf(sval[lane] - m) / denom;
        int e = sidx[lane];
        topk_idx[t * TOPK + lane] = e;
        topk_w[t * TOPK + lane] = w;
        atomicAdd(&counts[e], 1);
    }
}

__global__ void k_scan(const int* __restrict__ counts, int* __restrict__ offsets)
{
    if (threadIdx.x == 0) {
        int run = 0;
        for (int e = 0; e < NE; ++e) { offsets[e] = run; run += counts[e]; }
    }
}

// routes token-expert pairs to packed slots; records the inverse map
// tslot[t*8+k] = slot, used by the gather epilogue.
__global__ __launch_bounds__(256) void k_route(const int* __restrict__ topk_idx,
                                               const int* __restrict__ offsets,
                                               int* __restrict__ cursors,
                                               int* __restrict__ rtok,
                                               int* __restrict__ tslot)
{
    int i = blockIdx.x * 256 + threadIdx.x;
    int e = topk_idx[i];
    int pos = atomicAdd(&cursors[e], 1);
    int slot = offsets[e] + pos;
    rtok[slot] = i >> 3;
    tslot[i] = slot;
}

// ------------------------------------------------------------------
// conversion pre-pass (X and the two SHARED weights only; W1/W2 are
// consumed fp32 directly by the expert GEMMs since round 9)
__global__ __launch_bounds__(256) void k_cvt_x(const float* __restrict__ X,
                                               f16* __restrict__ Xh)
{
    int i = blockIdx.x * 256 + threadIdx.x;
    float4 v = ((const float4*)X)[i];
    f16x4 h = { (f16)v.x, (f16)v.y, (f16)v.z, (f16)v.w };
    ((f16x4*)Xh)[i] = h;
}

// fp32 [K][N] -> fp16 [N][K] (transpose).
__global__ __launch_bounds__(256) void k_cvt_t(const float* __restrict__ src,
                                               f16* __restrict__ dst,
                                               int K, int N)
{
    const int n0 = blockIdx.x * 64, k0 = blockIdx.y * 64;
    __shared__ f16 t[64][68];
    const int tid = threadIdx.x;
    #pragma unroll
    for (int i = 0; i < 4; ++i) {
        int idx = tid + i * 256;
        int r = idx >> 4, c4 = (idx & 15) * 4;
        float4 v = *(const float4*)&src[(size_t)(k0 + r) * N + n0 + c4];
        f16x4 h = { (f16)v.x, (f16)v.y, (f16)v.z, (f16)v.w };
        *(f16x4*)&t[r][c4] = h;
    }
    __syncthreads();
    #pragma unroll
    for (int i = 0; i < 4; ++i) {
        int idx = tid + i * 256;
        int nr = idx >> 4, kc = (idx & 15) * 4;
        f16x4 o = { t[kc][nr], t[kc + 1][nr], t[kc + 2][nr], t[kc + 3][nr] };
        *(f16x4*)&dst[(size_t)(n0 + nr) * K + k0 + kc] = o;
    }
}

// ------------------------------------------------------------------
// GEMM core: 128x128 tile, BK=32, 4 waves (2 M-halves x 2 N-halves),
// wave = 64x64 = acc[4][4]. 3-buffer pipeline, raw s_barrier (one per
// iter). LDS/buffer: As 128x32, Bs 128x32 f16 (16KB). Frag mapping
// (verified r0-r8): A[m=fr][k=q*8+j], B[n=fr][k=q*8+j], C/D col=fr,
// row=q*4+reg.
//
// LDS swizzle (verified r6-r8: SQ_LDS_BANK_CONFLICT = 0): logical chunk
// c (of 4x16B per row) stored at physical chunk c^((row>>1)&3).
// global_load_lds path: linear dest + inverse permute on the global
// source column (sc). reg-staged path: forward permute applied on the
// ds_write address. Reads always use qs = (q ^ ((fr>>1)&3))*8.

#define GEMM_PREAMBLE                                                        \
    const int tid = threadIdx.x, lane = tid & 63, wave = tid >> 6;           \
    const int wm = (wave >> 1) * 64, wn = (wave & 1) * 64;                   \
    const int fr = lane & 15, q = lane >> 4;                                 \
    const int qs = (q ^ ((fr >> 1) & 3)) * 8;                                \
    const int sr = lane >> 2;                                                \
    const int sc = ((lane & 3) ^ ((lane >> 3) & 3)) * 8;

#define GEMM_LDS                                                             \
    __shared__ alignas(16) f16 As[3][128 * 32];                              \
    __shared__ alignas(16) f16 Bs[3][128 * 32];

// one stage = 4 global_load_lds instructions per thread (16KB/tile).
#define GEMM_STAGE(si, ofs)                                                  \
    lds16(&As[si][wave * 32 * 32], gA0 + (ofs));                             \
    lds16(&As[si][(wave * 32 + 16) * 32], gA1 + (ofs));                      \
    lds16(&Bs[si][wave * 32 * 32], gB0 + (ofs));                             \
    lds16(&Bs[si][(wave * 32 + 16) * 32], gB1 + (ofs));

#define GEMM_MFMA(ri)                                                        \
    {                                                                        \
        f16x8 af[4], bf[4];                                                  \
        _Pragma("unroll")                                                    \
        for (int i = 0; i < 4; ++i)                                          \
            af[i] = *(const f16x8*)&As[ri][(wm + i * 16 + fr) * 32 + qs];    \
        _Pragma("unroll")                                                    \
        for (int j = 0; j < 4; ++j)                                          \
            bf[j] = *(const f16x8*)&Bs[ri][(wn + j * 16 + fr) * 32 + qs];    \
        _Pragma("unroll")                                                    \
        for (int i = 0; i < 4; ++i)                                          \
            _Pragma("unroll")                                                \
            for (int j = 0; j < 4; ++j)                                      \
                acc[i][j] = __builtin_amdgcn_mfma_f32_16x16x32_f16(          \
                    af[i], bf[j], acc[i][j], 0, 0, 0);                       \
    }

// Shared-GEMM pipelined K-loop (unchanged from r6-r8, verified).
#define GEMM_LOOP(KITERS)                                                    \
    GEMM_STAGE(0, 0)                                                         \
    GEMM_STAGE(1, 32)                                                        \
    _Pragma("unroll")                                                        \
    for (int t = 0; t < (KITERS); ++t) {                                     \
        if (t < (KITERS) - 1)                                                \
            asm volatile("s_waitcnt vmcnt(4)" ::: "memory");                 \
        else                                                                 \
            asm volatile("s_waitcnt vmcnt(0)" ::: "memory");                 \
        __builtin_amdgcn_s_barrier();                                        \
        asm volatile("" ::: "memory");                                       \
        if (t + 2 < (KITERS)) { GEMM_STAGE((t + 2) % 3, (t + 2) * 32) }      \
        GEMM_MFMA(t % 3)                                                     \
    }

// ---- expert-GEMM B path: fp32 W gathered per k-column, converted in
// registers (RNE casts), ds_written with write-side XOR swizzle. ----
// Per-lane assignment: bn = global n col, bkh = which 16-k half,
// brow = LDS B row, bxor = swizzle term (row>>1)&3.
#define EXP_B_PREAMBLE(N0, LDBV)                                             \
    const int bn = (N0) + wave * 32 + (lane & 31);                           \
    const int bkh = lane >> 5;                                               \
    const int brow = wave * 32 + (lane & 31);                                \
    const int bxor = (brow >> 1) & 3;                                        \
    const int ldb = (LDBV);                                                  \
    float bw[16];

#define EXP_ISSUE_B(krow)                                                    \
    _Pragma("unroll")                                                        \
    for (int kk = 0; kk < 16; ++kk)                                          \
        bw[kk] = gW[(size_t)((krow) + bkh * 16 + kk) * ldb + bn];

#define EXP_WRITE_B(si)                                                      \
    {                                                                        \
        f16x8 h0, h1;                                                        \
        _Pragma("unroll")                                                    \
        for (int kk = 0; kk < 8; ++kk) {                                     \
            h0[kk] = (f16)bw[kk];                                            \
            h1[kk] = (f16)bw[kk + 8];                                        \
        }                                                                    \
        *(f16x8*)&Bs[si][brow * 32 + ((bkh * 2 + 0) ^ bxor) * 8] = h0;       \
        *(f16x8*)&Bs[si][brow * 32 + ((bkh * 2 + 1) ^ bxor) * 8] = h1;       \
    }

#define EXP_ISSUE_A(si, ofs)                                                 \
    lds16(&As[si][wave * 32 * 32], gA0 + (ofs));                             \
    lds16(&As[si][(wave * 32 + 16) * 32], gA1 + (ofs));

// Expert K-loop. Race safety: B(t+1) written at iter t after barrier
// (t-1) (its previous readers, iter t-2, finished before that barrier);
// lgkmcnt(0) before barrier t publishes the writes; readers touch
// buffer t+1 only after barrier t+1. A path identical to r6-r8.
// vmcnt(0) at iter t drains exactly the stage-(t+1) batch issued at
// iter t-1 (1-iter cover).
#define GEMM_LOOP_WB(KITERS)                                                 \
    EXP_ISSUE_A(0, 0)                                                        \
    EXP_ISSUE_B(0)                                                           \
    asm volatile("s_waitcnt vmcnt(0)" ::: "memory");                         \
    EXP_WRITE_B(0)                                                           \
    EXP_ISSUE_A(1, 32)                                                       \
    EXP_ISSUE_B(32)                                                          \
    _Pragma("unroll")                                                        \
    for (int t = 0; t < (KITERS); ++t) {                                     \
        asm volatile("s_waitcnt vmcnt(0)" ::: "memory");                     \
        if (t + 1 < (KITERS)) { EXP_WRITE_B((t + 1) % 3) }                   \
        asm volatile("s_waitcnt lgkmcnt(0)" ::: "memory");                   \
        __builtin_amdgcn_s_barrier();                                        \
        asm volatile("" ::: "memory");                                       \
        if (t + 2 < (KITERS)) {                                              \
            EXP_ISSUE_A((t + 2) % 3, (t + 2) * 32)                           \
            EXP_ISSUE_B((t + 2) * 32)                                        \
        }                                                                    \
        GEMM_MFMA(t % 3)                                                     \
    }

// shared GEMM1: H1 = silu(Xh @ Ws1), fp16. M=2048 N=4096 K=1024.
__global__ __launch_bounds__(256) void g_shared1(const f16* __restrict__ Xh,
                                                 const f16* __restrict__ Bt,  // [FF][HD]
                                                 f16* __restrict__ H1)
{
    GEMM_LDS
    GEMM_PREAMBLE
    const int m0 = blockIdx.y * 128, n0 = blockIdx.x * 128;
    const f16* gA0 = Xh + (size_t)(m0 + wave * 32 + sr) * HD + sc;
    const f16* gA1 = gA0 + (size_t)16 * HD;
    const f16* gB0 = Bt + (size_t)(n0 + wave * 32 + sr) * HD + sc;
    const f16* gB1 = gB0 + (size_t)16 * HD;

    f32x4 acc[4][4] = {};
    GEMM_LOOP(32)

    #pragma unroll
    for (int i = 0; i < 4; ++i)
        #pragma unroll
        for (int j = 0; j < 4; ++j)
            #pragma unroll
            for (int r = 0; r < 4; ++r) {
                int m = m0 + wm + i * 16 + q * 4 + r;
                int n = n0 + wn + j * 16 + fr;
                float v = acc[i][j][r];
                H1[(size_t)m * FF + n] = (f16)(v / (1.f + expf(-v)));
            }
}

// shared GEMM2: S2p[z] = H1 @ Ws2 K-slice, fp32 plain stores.
// M=2048 N=1024 K=4096 split-K=4.
__global__ __launch_bounds__(256) void g_shared2(const f16* __restrict__ H1,
                                                 const f16* __restrict__ Bt,  // [HD][FF]
                                                 float* __restrict__ S2p)
{
    GEMM_LDS
    GEMM_PREAMBLE
    const int m0 = blockIdx.y * 128, n0 = blockIdx.x * 128;
    const int kbase = blockIdx.z * (FF / 4);
    float* P = S2p + (size_t)blockIdx.z * NT * HD;
    const f16* gA0 = H1 + (size_t)(m0 + wave * 32 + sr) * FF + kbase + sc;
    const f16* gA1 = gA0 + (size_t)16 * FF;
    const f16* gB0 = Bt + (size_t)(n0 + wave * 32 + sr) * FF + kbase + sc;
    const f16* gB1 = gB0 + (size_t)16 * FF;

    f32x4 acc[4][4] = {};
    GEMM_LOOP(32)

    #pragma unroll
    for (int i = 0; i < 4; ++i)
        #pragma unroll
        for (int j = 0; j < 4; ++j)
            #pragma unroll
            for (int r = 0; r < 4; ++r) {
                int m = m0 + wm + i * 16 + q * 4 + r;
                int n = n0 + wn + j * 16 + fr;
                P[(size_t)m * HD + n] = acc[i][j][r];
            }
}

// expert GEMM1: Hx[slot] = silu(Xh[rtok[slot]] @ W1[e]) fp16.
// K=1024 N=512. B = W1[e] fp32 [H][M] consumed directly (k-col gather).
// 1-D grid 4096, XCD-residue swizzle: lid = r + 8*(g*64 + k), e = g*8+r,
// k = y*4+x (y<16 covers cnt<=2048, x<4 n-blocks).
__global__ __launch_bounds__(256) void g_exp1(const f16* __restrict__ Xh,
                                              const float* __restrict__ W1, // [E][H][M]
                                              const int* __restrict__ counts,
                                              const int* __restrict__ offsets,
                                              const int* __restrict__ rtok,
                                              f16* __restrict__ Hx)
{
    const int lid = blockIdx.x;
    const int rres = lid & 7;
    const int t2 = lid >> 3;
    const int k = t2 & 63;
    const int g = t2 >> 6;
    const int e = g * 8 + rres;
    const int cnt = counts[e];
    const int mt = (k >> 2) * 128;
    if (mt >= cnt) return;
    const int off = offsets[e];
    const int n0 = (k & 3) * 128;
    const float* gW = W1 + (size_t)e * HD * MD;

    GEMM_LDS
    GEMM_PREAMBLE
    EXP_B_PREAMBLE(n0, MD)

    int rm0 = mt + wave * 32 + sr;
    int rm1 = rm0 + 16;
    int s0 = off + (rm0 < cnt ? rm0 : cnt - 1);
    int s1 = off + (rm1 < cnt ? rm1 : cnt - 1);
    const f16* gA0 = Xh + (size_t)rtok[s0] * HD + sc;
    const f16* gA1 = Xh + (size_t)rtok[s1] * HD + sc;

    f32x4 acc[4][4] = {};
    GEMM_LOOP_WB(32)

    #pragma unroll
    for (int i = 0; i < 4; ++i)
        #pragma unroll
        for (int j = 0; j < 4; ++j)
            #pragma unroll
            for (int r = 0; r < 4; ++r) {
                int m_in = mt + wm + i * 16 + q * 4 + r;
                if (m_in < cnt) {
                    int n = n0 + wn + j * 16 + fr;
                    float v = acc[i][j][r];
                    Hx[(size_t)(off + m_in) * MD + n] = (f16)(v / (1.f + expf(-v)));
                }
            }
}

// expert GEMM2: Hy[slot] = Hx[slot] @ W2[e], fp16 plain stores.
// K=512 N=1024. B = W2[e] fp32 [M][H] consumed directly.
// 1-D grid 8192, same XCD-residue swizzle: lid = r + 8*(g*128 + k),
// e = g*8+r, k = y*8+x (y<16, x<8 n-blocks).
__global__ __launch_bounds__(256) void g_exp2(const f16* __restrict__ Hx,
                                              const float* __restrict__ W2, // [E][M][H]
                                              const int* __restrict__ counts,
                                              const int* __restrict__ offsets,
                                              f16* __restrict__ Hy)
{
    const int lid = blockIdx.x;
    const int rres = lid & 7;
    const int t2 = lid >> 3;
    const int k = t2 & 127;
    const int g = t2 >> 7;
    const int e = g * 8 + rres;
    const int cnt = counts[e];
    const int mt = (k >> 3) * 128;
    if (mt >= cnt) return;
    const int off = offsets[e];
    const int n0 = (k & 7) * 128;
    const float* gW = W2 + (size_t)e * MD * HD;

    GEMM_LDS
    GEMM_PREAMBLE
    EXP_B_PREAMBLE(n0, HD)

    // A rows are packed slots; Hx pad rows (128) make OOB reads safe
    // (masked at C).
    const f16* gA0 = Hx + (size_t)(off + mt + wave * 32 + sr) * MD + sc;
    const f16* gA1 = gA0 + (size_t)16 * MD;

    f32x4 acc[4][4] = {};
    GEMM_LOOP_WB(16)

    #pragma unroll
    for (int i = 0; i < 4; ++i)
        #pragma unroll
        for (int j = 0; j < 4; ++j)
            #pragma unroll
            for (int r = 0; r < 4; ++r) {
                int m_in = mt + wm + i * 16 + q * 4 + r;
                if (m_in < cnt) {
                    int n = n0 + wn + j * 16 + fr;
                    Hy[(size_t)(off + m_in) * HD + n] = (f16)acc[i][j][r];
                }
            }
}

// gather epilogue: Out[t][h] = sum_z S2p[z][t][h]
//                            + sum_k topk_w[t,k] * Hy[tslot[t,k]][h].
// One block per token, 256 threads x float4. Pure streaming (~75 MB).
__global__ __launch_bounds__(256) void k_gather(const float* __restrict__ S2p,
                                                const f16* __restrict__ Hy,
                                                const int* __restrict__ tslot,
                                                const float* __restrict__ tw,
                                                float* __restrict__ Out)
{
    const int t = blockIdx.x;
    const int tid = threadIdx.x;
    __shared__ int ss[TOPK];
    __shared__ float sw[TOPK];
    if (tid < TOPK) {
        ss[tid] = tslot[t * TOPK + tid];
        sw[tid] = tw[t * TOPK + tid];
    }
    __syncthreads();
    const int h = tid * 4;
    float4 a = *(const float4*)&S2p[(size_t)t * HD + h];
    #pragma unroll
    for (int z = 1; z < 4; ++z) {
        float4 b = *(const float4*)&S2p[(size_t)z * NT * HD + (size_t)t * HD + h];
        a.x += b.x; a.y += b.y; a.z += b.z; a.w += b.w;
    }
    #pragma unroll
    for (int kk = 0; kk < TOPK; ++kk) {
        f16x4 y = *(const f16x4*)&Hy[(size_t)ss[kk] * HD + h];
        float w = sw[kk];
        a.x += w * (float)y[0];
        a.y += w * (float)y[1];
        a.z += w * (float)y[2];
        a.w += w * (float)y[3];
    }
    *(float4*)&Out[(size_t)t * HD + h] = a;
}

// ------------------------------------------------------------------
extern "C" void kernel_launch(void* const* d_in, const int* in_sizes, int n_in,
                              void* d_out, int out_size, void* d_ws, size_t ws_size,
                              hipStream_t stream)
{
    (void)in_sizes; (void)n_in; (void)out_size; (void)ws_size;
    const float* X   = (const float*)d_in[0];
    const float* Ws1 = (const float*)d_in[1];
    const float* Ws2 = (const float*)d_in[2];
    const float* Wg  = (const float*)d_in[3];
    const float* W1  = (const float*)d_in[4];
    const float* W2  = (const float*)d_in[5];
    float* out = (float*)d_out;
    float* logits = out + (size_t)NT * HD;

    char* ws = (char*)d_ws;
    f16*   h1       = (f16*)(ws + O_H1);
    f16*   hx       = (f16*)(ws + O_HX);
    int*   topk_idx = (int*)(ws + O_TOPKI);
    float* topk_w   = (float*)(ws + O_TOPKW);
    int*   counts   = (int*)(ws + O_COUNTS);
    int*   cursors  = (int*)(ws + O_CURSORS);
    int*   offsets  = (int*)(ws + O_OFFSETS);
    int*   rtok     = (int*)(ws + O_RTOK);
    int*   tslot    = (int*)(ws + O_TSLOT);
    f16*   xh       = (f16*)(ws + O_XH);
    f16*   ws1t     = (f16*)(ws + O_WS1T);
    f16*   ws2t     = (f16*)(ws + O_WS2T);
    f16*   hy       = (f16*)(ws + O_HY);
    float* s2p      = (float*)(ws + O_S2P);

    hipMemsetAsync(counts, 0, 512, stream);   // counts + cursors

    k_router<<<NT / 4, 256, 0, stream>>>(X, Wg, logits);
    k_topk<<<NT, 64, 0, stream>>>(logits, topk_idx, topk_w, counts);
    k_scan<<<1, 64, 0, stream>>>(counts, offsets);
    k_route<<<NT * TOPK / 256, 256, 0, stream>>>(topk_idx, offsets, cursors, rtok, tslot);

    // conversion pre-pass (shared weights + activations only)
    k_cvt_x<<<NT * HD / 1024, 256, 0, stream>>>(X, xh);
    k_cvt_t<<<dim3(FF / 64, HD / 64), 256, 0, stream>>>(Ws1, ws1t, HD, FF);
    k_cvt_t<<<dim3(HD / 64, FF / 64), 256, 0, stream>>>(Ws2, ws2t, FF, HD);

    g_shared1<<<dim3(FF / 128, NT / 128), 256, 0, stream>>>(xh, ws1t, h1);
    g_shared2<<<dim3(HD / 128, NT / 128, 4), 256, 0, stream>>>(h1, ws2t, s2p);
    g_exp1<<<4096, 256, 0, stream>>>(xh, W1, counts, offsets, rtok, hx);
    g_exp2<<<8192, 256, 0, stream>>>(hx, W2, counts, offsets, hy);
    k_gather<<<NT, 256, 0, stream>>>(s2p, hy, tslot, topk_w, out);
}